// Round 1
// baseline (8344.918 us; speedup 1.0000x reference)
//
#include <hip/hip_runtime.h>

typedef unsigned short u16;
typedef unsigned int   u32;
typedef __attribute__((ext_vector_type(8))) __bf16 bf16x8;
typedef __attribute__((ext_vector_type(4))) float  f32x4;

#define DEV static __device__ __forceinline__

DEV u16 f2bf(float f) {
    u32 u = __float_as_uint(f);
    u = (u + 0x7fffu + ((u >> 16) & 1u)) >> 16;
    return (u16)u;
}
DEV float bf2f(u16 b) { return __uint_as_float(((u32)b) << 16); }
DEV bf16x8 ldfrag(const u16* p) { return *reinterpret_cast<const bf16x8*>(p); }

// ---------------------------------------------------------------- cvt f32->bf16
__global__ __launch_bounds__(256) void k_cvt(const float* __restrict__ in, u16* __restrict__ out, int n) {
    int i = (blockIdx.x * 256 + threadIdx.x) * 4;
    if (i < n) {
        float4 v = *reinterpret_cast<const float4*>(in + i);
        u16 o0 = f2bf(v.x), o1 = f2bf(v.y), o2 = f2bf(v.z), o3 = f2bf(v.w);
        ushort4 o; o.x = o0; o.y = o1; o.z = o2; o.w = o3;
        *reinterpret_cast<ushort4*>(out + i) = o;
    }
}

// ------------------------------------------- transpose f32 in[R][C] -> bf16 out[C][R]
__global__ __launch_bounds__(256) void k_tr_f2b(const float* __restrict__ in, u16* __restrict__ out,
                                                int R, int C) {
    __shared__ float t[32][33];
    int c0 = blockIdx.x * 32, r0 = blockIdx.y * 32;
    int tx = threadIdx.x % 32, ty = threadIdx.x / 32;   // ty 0..7
    for (int i = 0; i < 32; i += 8)
        t[ty + i][tx] = in[(r0 + ty + i) * C + c0 + tx];
    __syncthreads();
    for (int i = 0; i < 32; i += 8)
        out[(size_t)(c0 + ty + i) * R + r0 + tx] = f2bf(t[tx][ty + i]);
}

// ---------------- transpose V (cols 1024..1535 of QKV) -> Vt[b][h][s] (bf16)
__global__ __launch_bounds__(256) void k_tr_v(const u16* __restrict__ qkv, u16* __restrict__ vt) {
    __shared__ u16 t[32][33];
    int b = blockIdx.z;
    int s0 = blockIdx.x * 32, h0 = blockIdx.y * 32;
    int tx = threadIdx.x % 32, ty = threadIdx.x / 32;
    for (int i = 0; i < 32; i += 8)
        t[ty + i][tx] = qkv[(size_t)(b * 1024 + s0 + ty + i) * 1536 + 1024 + h0 + tx];
    __syncthreads();
    for (int i = 0; i < 32; i += 8)
        vt[(size_t)b * 512 * 1024 + (size_t)(h0 + ty + i) * 1024 + s0 + tx] = t[tx][ty + i];
}

// ---------------- generic bf16 GEMM: C[M,N] = A[M,K] * Bt[N,K]^T (+bias), bf16 out
// 128x128 block, 4 waves in 2x2, direct-from-global fragments (weights L2-resident).
__global__ __launch_bounds__(256) void k_gemm(const u16* __restrict__ A, const u16* __restrict__ Bt,
                                              u16* __restrict__ Cb, const float* __restrict__ bias,
                                              int M, int N, int K, int ldc) {
    int mtiles = M >> 7;
    int mt = blockIdx.x % mtiles, nt = blockIdx.x / mtiles;
    int m0 = mt << 7, n0 = nt << 7;
    int lane = threadIdx.x & 63, wid = threadIdx.x >> 6;
    int wm = (wid >> 1) * 64, wn = (wid & 1) * 64;
    int ls = lane & 15, g = lane >> 4;
    f32x4 acc[4][4] = {};
    const u16* Ap = A + (size_t)(m0 + wm + ls) * K + g * 8;
    const u16* Bp = Bt + (size_t)(n0 + wn + ls) * K + g * 8;
    for (int k0 = 0; k0 < K; k0 += 32) {
        bf16x8 a[4], b[4];
        #pragma unroll
        for (int i = 0; i < 4; i++) a[i] = ldfrag(Ap + (size_t)i * 16 * K + k0);
        #pragma unroll
        for (int j = 0; j < 4; j++) b[j] = ldfrag(Bp + (size_t)j * 16 * K + k0);
        #pragma unroll
        for (int i = 0; i < 4; i++)
            #pragma unroll
            for (int j = 0; j < 4; j++)
                acc[i][j] = __builtin_amdgcn_mfma_f32_16x16x32_bf16(a[i], b[j], acc[i][j], 0, 0, 0);
    }
    #pragma unroll
    for (int i = 0; i < 4; i++)
        #pragma unroll
        for (int j = 0; j < 4; j++) {
            int col = n0 + wn + j * 16 + ls;
            float bv = bias ? bias[col] : 0.f;
            #pragma unroll
            for (int r = 0; r < 4; r++) {
                int row = m0 + wm + i * 16 + g * 4 + r;
                Cb[(size_t)row * ldc + col] = f2bf(acc[i][j][r] + bv);
            }
        }
}

// ---------------- fused attention: per (batch, 16-row q tile)
// phase1: S=Q K^T in regs (wave w: cols w*256..+256); softmax via shfl; P->LDS (swizzled bf16)
// phase2: O = P V via Vt; divide by row sum; write attnO bf16
__global__ __launch_bounds__(256) void k_attn(const u16* __restrict__ qkv, const u16* __restrict__ vt,
                                              u16* __restrict__ attnO) {
    __shared__ u16 P[16 * 1024];
    __shared__ float mbuf[4][16], lbuf[4][16];
    int b = blockIdx.x >> 6, qt = blockIdx.x & 63;
    int q0 = qt * 16;
    int lane = threadIdx.x & 63, w = threadIdx.x >> 6;
    int ls = lane & 15, g = lane >> 4;
    const float sc = 0.04419417382f;  // 1/sqrt(512)

    f32x4 acc[16] = {};
    const u16* Qp = qkv + (size_t)(b * 1024 + q0 + ls) * 1536 + g * 8;
    const u16* Kp = qkv + (size_t)(b * 1024 + w * 256 + ls) * 1536 + 512 + g * 8;
    for (int k0 = 0; k0 < 512; k0 += 32) {
        bf16x8 a = ldfrag(Qp + k0);
        #pragma unroll
        for (int f = 0; f < 16; f++) {
            bf16x8 bb = ldfrag(Kp + (size_t)f * 16 * 1536 + k0);
            acc[f] = __builtin_amdgcn_mfma_f32_16x16x32_bf16(a, bb, acc[f], 0, 0, 0);
        }
    }
    // row max over this wave's 256 cols (lane holds rows g*4+r, col = w*256+f*16+ls)
    float mx[4] = {-1e30f, -1e30f, -1e30f, -1e30f};
    #pragma unroll
    for (int f = 0; f < 16; f++)
        #pragma unroll
        for (int r = 0; r < 4; r++) mx[r] = fmaxf(mx[r], acc[f][r]);
    #pragma unroll
    for (int d = 1; d < 16; d <<= 1)
        #pragma unroll
        for (int r = 0; r < 4; r++) mx[r] = fmaxf(mx[r], __shfl_xor(mx[r], d, 64));
    if (ls == 0)
        #pragma unroll
        for (int r = 0; r < 4; r++) mbuf[w][g * 4 + r] = mx[r];
    __syncthreads();
    float m[4];
    #pragma unroll
    for (int r = 0; r < 4; r++) {
        int row = g * 4 + r;
        m[r] = fmaxf(fmaxf(mbuf[0][row], mbuf[1][row]), fmaxf(mbuf[2][row], mbuf[3][row])) * sc;
    }
    float sum[4] = {0.f, 0.f, 0.f, 0.f};
    #pragma unroll
    for (int f = 0; f < 16; f++)
        #pragma unroll
        for (int r = 0; r < 4; r++) {
            int row = g * 4 + r, col = w * 256 + f * 16 + ls;
            float e = __expf(acc[f][r] * sc - m[r]);
            sum[r] += e;
            P[(row * 1024 + col) ^ ((row & 7) << 3)] = f2bf(e);   // XOR-swizzle (G4)
        }
    #pragma unroll
    for (int d = 1; d < 16; d <<= 1)
        #pragma unroll
        for (int r = 0; r < 4; r++) sum[r] += __shfl_xor(sum[r], d, 64);
    if (ls == 0)
        #pragma unroll
        for (int r = 0; r < 4; r++) lbuf[w][g * 4 + r] = sum[r];
    __syncthreads();

    // phase 2: wave w -> out cols w*128..+128
    f32x4 o[8] = {};
    const bf16x8* Pv = reinterpret_cast<const bf16x8*>(P);
    const u16* Vp = vt + (size_t)b * 512 * 1024 + (size_t)(w * 128 + ls) * 1024 + g * 8;
    for (int k0 = 0; k0 < 1024; k0 += 32) {
        bf16x8 a = Pv[(ls * 128 + (k0 >> 3) + g) ^ (ls & 7)];
        #pragma unroll
        for (int q = 0; q < 8; q++) {
            bf16x8 bb = ldfrag(Vp + (size_t)q * 16 * 1024 + k0);
            o[q] = __builtin_amdgcn_mfma_f32_16x16x32_bf16(a, bb, o[q], 0, 0, 0);
        }
    }
    #pragma unroll
    for (int q = 0; q < 8; q++) {
        int col = w * 128 + q * 16 + ls;
        #pragma unroll
        for (int r = 0; r < 4; r++) {
            int row = g * 4 + r;
            float l = lbuf[0][row] + lbuf[1][row] + lbuf[2][row] + lbuf[3][row];
            attnO[(size_t)(b * 1024 + q0 + row) * 512 + col] = f2bf(o[q][r] / l);
        }
    }
}

// ---------------- proj Wo + residual(emb) + LayerNorm -> out1 (f32 + bf16)
__global__ __launch_bounds__(256) void k_projln(const u16* __restrict__ attnO, const u16* __restrict__ WoT,
                                                const float* __restrict__ emb, const float* __restrict__ gamma,
                                                const float* __restrict__ beta, float* __restrict__ out1f,
                                                u16* __restrict__ out1b) {
    __shared__ float buf[16][512];
    int m0 = blockIdx.x * 16;
    int lane = threadIdx.x & 63, w = threadIdx.x >> 6;
    int ls = lane & 15, g = lane >> 4;
    f32x4 acc[8] = {};
    const u16* Ap = attnO + (size_t)(m0 + ls) * 512 + g * 8;
    const u16* Bp = WoT + (size_t)(w * 128 + ls) * 512 + g * 8;
    for (int k0 = 0; k0 < 512; k0 += 32) {
        bf16x8 a = ldfrag(Ap + k0);
        #pragma unroll
        for (int q = 0; q < 8; q++) {
            bf16x8 bb = ldfrag(Bp + (size_t)q * 16 * 512 + k0);
            acc[q] = __builtin_amdgcn_mfma_f32_16x16x32_bf16(a, bb, acc[q], 0, 0, 0);
        }
    }
    #pragma unroll
    for (int q = 0; q < 8; q++) {
        int col = w * 128 + q * 16 + ls;
        #pragma unroll
        for (int r = 0; r < 4; r++) {
            int row = g * 4 + r;
            buf[row][col] = acc[q][r] + emb[(size_t)(m0 + row) * 512 + col];
        }
    }
    __syncthreads();
    int row = threadIdx.x >> 4, c0 = threadIdx.x & 15;
    float s = 0.f, s2 = 0.f;
    for (int c = c0; c < 512; c += 16) { float x = buf[row][c]; s += x; s2 += x * x; }
    #pragma unroll
    for (int d = 1; d < 16; d <<= 1) { s += __shfl_xor(s, d, 64); s2 += __shfl_xor(s2, d, 64); }
    float mu = s * (1.f / 512.f);
    float var = s2 * (1.f / 512.f) - mu * mu;
    float rs = rsqrtf(var + 1e-3f);
    for (int c = c0; c < 512; c += 16) {
        float y = gamma[c] * (buf[row][c] - mu) * rs + beta[c];
        out1f[(size_t)(m0 + row) * 512 + c] = y;
        out1b[(size_t)(m0 + row) * 512 + c] = f2bf(y);
    }
}

// ---------------- zero h0 / c0
__global__ __launch_bounds__(256) void k_init(u16* hA, float* c) {
    int i = blockIdx.x * 256 + threadIdx.x;
    if (i < 16 * 512) { hA[i] = 0; c[i] = 0.f; }
}

// ---------------- one LSTM step: z = xp[:,s,:] + h @ R ; gates ; h,c update
// 16 blocks, block owns 32 u-cols (all 4 gates); wave w computes gate w.
__global__ __launch_bounds__(256) void k_step(const u16* __restrict__ xp, const u16* __restrict__ rT,
                                              const u16* __restrict__ hprev, u16* __restrict__ hnext,
                                              float* __restrict__ c, float* __restrict__ hseq, int s) {
    __shared__ float z[16][128];
    int u0 = blockIdx.x * 32;
    int lane = threadIdx.x & 63, w = threadIdx.x >> 6;
    int ls = lane & 15, g = lane >> 4;
    f32x4 acc[2] = {};
    const u16* Ap = hprev + ls * 512 + g * 8;
    const u16* Bp = rT + (size_t)(w * 512 + u0 + ls) * 512 + g * 8;
    #pragma unroll
    for (int k0 = 0; k0 < 512; k0 += 32) {
        bf16x8 a = ldfrag(Ap + k0);
        #pragma unroll
        for (int q = 0; q < 2; q++) {
            bf16x8 bb = ldfrag(Bp + (size_t)q * 16 * 512 + k0);
            acc[q] = __builtin_amdgcn_mfma_f32_16x16x32_bf16(a, bb, acc[q], 0, 0, 0);
        }
    }
    #pragma unroll
    for (int q = 0; q < 2; q++)
        #pragma unroll
        for (int r = 0; r < 4; r++)
            z[g * 4 + r][w * 32 + q * 16 + ls] = acc[q][r];
    __syncthreads();
    int idx = threadIdx.x;
    #pragma unroll
    for (int it = 0; it < 2; it++, idx += 256) {
        int b = idx >> 5, uu = idx & 31, u = u0 + uu;
        const u16* xr = xp + (size_t)(b * 1024 + s) * 2048;
        float zi = z[b][uu]      + bf2f(xr[u]);
        float zf = z[b][32 + uu] + bf2f(xr[512 + u]);
        float zg = z[b][64 + uu] + bf2f(xr[1024 + u]);
        float zo = z[b][96 + uu] + bf2f(xr[1536 + u]);
        float ii = 1.f / (1.f + __expf(-zi));
        float ff = 1.f / (1.f + __expf(-zf));
        float gg = fmaxf(zg, 0.f);
        float oo = 1.f / (1.f + __expf(-zo));
        int ci = b * 512 + u;
        float cn = ff * c[ci] + ii * gg;
        c[ci] = cn;
        float h = oo * fmaxf(cn, 0.f);
        hseq[(size_t)(b * 1024 + s) * 512 + u] = h;
        hnext[b * 512 + u] = f2bf(h);
    }
}

// ---------------- final LN in place on d_out: out = LN(d_out + out1f)
__global__ __launch_bounds__(256) void k_finln(float* __restrict__ io, const float* __restrict__ res,
                                               const float* __restrict__ gamma, const float* __restrict__ beta) {
    int m0 = blockIdx.x * 16;
    int row = threadIdx.x >> 4, c0 = threadIdx.x & 15;
    size_t base = (size_t)(m0 + row) * 512;
    float x[32];
    float s = 0.f, s2 = 0.f;
    #pragma unroll
    for (int i = 0; i < 32; i++) {
        int cc = c0 + i * 16;
        x[i] = io[base + cc] + res[base + cc];
        s += x[i]; s2 += x[i] * x[i];
    }
    #pragma unroll
    for (int d = 1; d < 16; d <<= 1) { s += __shfl_xor(s, d, 64); s2 += __shfl_xor(s2, d, 64); }
    float mu = s * (1.f / 512.f);
    float var = s2 * (1.f / 512.f) - mu * mu;
    float rs = rsqrtf(var + 1e-3f);
    #pragma unroll
    for (int i = 0; i < 32; i++) {
        int cc = c0 + i * 16;
        io[base + cc] = gamma[cc] * (x[i] - mu) * rs + beta[cc];
    }
}

extern "C" void kernel_launch(void* const* d_in, const int* in_sizes, int n_in,
                              void* d_out, int out_size, void* d_ws, size_t ws_size,
                              hipStream_t stream) {
    (void)in_sizes; (void)n_in; (void)out_size; (void)ws_size;
    const float* emb   = (const float*)d_in[0];
    const float* Wq    = (const float*)d_in[1];
    const float* Wk    = (const float*)d_in[2];
    const float* Wv    = (const float*)d_in[3];
    const float* Wo    = (const float*)d_in[4];
    const float* gamma = (const float*)d_in[5];
    const float* beta  = (const float*)d_in[6];
    const float* lk    = (const float*)d_in[7];
    const float* lr    = (const float*)d_in[8];
    const float* lb    = (const float*)d_in[9];

    char* w = (char*)d_ws;
    size_t o = 0;
    u16* WqkvT = (u16*)(w + o); o += (size_t)1536 * 512 * 2;
    u16* WoT   = (u16*)(w + o); o += (size_t)512 * 512 * 2;
    u16* kT    = (u16*)(w + o); o += (size_t)2048 * 512 * 2;
    u16* rT    = (u16*)(w + o); o += (size_t)2048 * 512 * 2;
    u16* Xbf   = (u16*)(w + o); o += (size_t)16384 * 512 * 2;     // reused as attnO
    u16* QKV   = (u16*)(w + o); o += (size_t)16384 * 1536 * 2;    // reused (with Vt) as xp
    u16* Vt    = (u16*)(w + o); o += (size_t)16 * 512 * 1024 * 2;
    float* out1f = (float*)(w + o); o += (size_t)16384 * 512 * 4;
    u16* out1b = (u16*)(w + o); o += (size_t)16384 * 512 * 2;
    u16* hA    = (u16*)(w + o); o += (size_t)16 * 512 * 2;
    u16* hB    = (u16*)(w + o); o += (size_t)16 * 512 * 2;
    float* cst = (float*)(w + o); o += (size_t)16 * 512 * 4;
    u16* attnO = Xbf;   // Xbf dead after QKV GEMM
    u16* xp    = QKV;   // QKV+Vt dead after attention; 50.3+16.8 MB == 67.1 MB needed
    float* outp = (float*)d_out;

    k_cvt<<<8192, 256, 0, stream>>>(emb, Xbf, 16384 * 512);
    k_tr_f2b<<<dim3(16, 16), 256, 0, stream>>>(Wq, WqkvT, 512, 512);
    k_tr_f2b<<<dim3(16, 16), 256, 0, stream>>>(Wk, WqkvT + 512 * 512, 512, 512);
    k_tr_f2b<<<dim3(16, 16), 256, 0, stream>>>(Wv, WqkvT + 1024 * 512, 512, 512);
    k_tr_f2b<<<dim3(16, 16), 256, 0, stream>>>(Wo, WoT, 512, 512);
    k_tr_f2b<<<dim3(64, 16), 256, 0, stream>>>(lk, kT, 512, 2048);
    k_tr_f2b<<<dim3(64, 16), 256, 0, stream>>>(lr, rT, 512, 2048);
    k_gemm<<<128 * 12, 256, 0, stream>>>(Xbf, WqkvT, QKV, nullptr, 16384, 1536, 512, 1536);
    k_tr_v<<<dim3(32, 16, 16), 256, 0, stream>>>(QKV, Vt);
    k_attn<<<1024, 256, 0, stream>>>(QKV, Vt, attnO);
    k_projln<<<1024, 256, 0, stream>>>(attnO, WoT, emb, gamma, beta, out1f, out1b);
    k_gemm<<<128 * 16, 256, 0, stream>>>(out1b, kT, xp, lb, 16384, 2048, 512, 2048);
    k_init<<<32, 256, 0, stream>>>(hA, cst);
    for (int s = 0; s < 1024; s++) {
        const u16* hp = (s & 1) ? hB : hA;
        u16* hn = (s & 1) ? hA : hB;
        k_step<<<16, 256, 0, stream>>>(xp, rT, hp, hn, cst, outp, s);
    }
    k_finln<<<1024, 256, 0, stream>>>(outp, out1f, gamma, beta);
}

// Round 2
// 6191.694 us; speedup vs baseline: 1.3478x; 1.3478x over previous
//
#include <hip/hip_runtime.h>

typedef unsigned short u16;
typedef unsigned int   u32;
typedef __attribute__((ext_vector_type(8))) __bf16 bf16x8;
typedef __attribute__((ext_vector_type(4))) float  f32x4;

#define DEV static __device__ __forceinline__

DEV u16 f2bf(float f) {
    u32 u = __float_as_uint(f);
    u = (u + 0x7fffu + ((u >> 16) & 1u)) >> 16;
    return (u16)u;
}
DEV float bf2f(u16 b) { return __uint_as_float(((u32)b) << 16); }
DEV bf16x8 ldfrag(const u16* p) { return *reinterpret_cast<const bf16x8*>(p); }

// ---------------------------------------------------------------- cvt f32->bf16
__global__ __launch_bounds__(256) void k_cvt(const float* __restrict__ in, u16* __restrict__ out, int n) {
    int i = (blockIdx.x * 256 + threadIdx.x) * 4;
    if (i < n) {
        float4 v = *reinterpret_cast<const float4*>(in + i);
        ushort4 o; o.x = f2bf(v.x); o.y = f2bf(v.y); o.z = f2bf(v.z); o.w = f2bf(v.w);
        *reinterpret_cast<ushort4*>(out + i) = o;
    }
}

// ------------------------------------------- transpose f32 in[R][C] -> bf16 out[C][R]
__global__ __launch_bounds__(256) void k_tr_f2b(const float* __restrict__ in, u16* __restrict__ out,
                                                int R, int C) {
    __shared__ float t[32][33];
    int c0 = blockIdx.x * 32, r0 = blockIdx.y * 32;
    int tx = threadIdx.x % 32, ty = threadIdx.x / 32;   // ty 0..7
    for (int i = 0; i < 32; i += 8)
        t[ty + i][tx] = in[(r0 + ty + i) * C + c0 + tx];
    __syncthreads();
    for (int i = 0; i < 32; i += 8)
        out[(size_t)(c0 + ty + i) * R + r0 + tx] = f2bf(t[tx][ty + i]);
}

// ---------------- transpose V (cols 1024..1535 of QKV) -> Vt[b][h][s] (bf16)
__global__ __launch_bounds__(256) void k_tr_v(const u16* __restrict__ qkv, u16* __restrict__ vt) {
    __shared__ u16 t[32][33];
    int b = blockIdx.z;
    int s0 = blockIdx.x * 32, h0 = blockIdx.y * 32;
    int tx = threadIdx.x % 32, ty = threadIdx.x / 32;
    for (int i = 0; i < 32; i += 8)
        t[ty + i][tx] = qkv[(size_t)(b * 1024 + s0 + ty + i) * 1536 + 1024 + h0 + tx];
    __syncthreads();
    for (int i = 0; i < 32; i += 8)
        vt[(size_t)b * 512 * 1024 + (size_t)(h0 + ty + i) * 1024 + s0 + tx] = t[tx][ty + i];
}

// ---------------- generic bf16 GEMM: C[M,N] = A[M,K] * Bt[N,K]^T (+bias), bf16 out
// xp_mode: remap store to per-block LSTM layout xpp[j][s][b][gate][uu]
__global__ __launch_bounds__(256) void k_gemm(const u16* __restrict__ A, const u16* __restrict__ Bt,
                                              u16* __restrict__ Cb, const float* __restrict__ bias,
                                              int M, int N, int K, int ldc, int xp_mode) {
    int mtiles = M >> 7;
    int mt = blockIdx.x % mtiles, nt = blockIdx.x / mtiles;
    int m0 = mt << 7, n0 = nt << 7;
    int lane = threadIdx.x & 63, wid = threadIdx.x >> 6;
    int wm = (wid >> 1) * 64, wn = (wid & 1) * 64;
    int ls = lane & 15, g = lane >> 4;
    f32x4 acc[4][4] = {};
    const u16* Ap = A + (size_t)(m0 + wm + ls) * K + g * 8;
    const u16* Bp = Bt + (size_t)(n0 + wn + ls) * K + g * 8;
    for (int k0 = 0; k0 < K; k0 += 32) {
        bf16x8 a[4], b[4];
        #pragma unroll
        for (int i = 0; i < 4; i++) a[i] = ldfrag(Ap + (size_t)i * 16 * K + k0);
        #pragma unroll
        for (int j = 0; j < 4; j++) b[j] = ldfrag(Bp + (size_t)j * 16 * K + k0);
        #pragma unroll
        for (int i = 0; i < 4; i++)
            #pragma unroll
            for (int j = 0; j < 4; j++)
                acc[i][j] = __builtin_amdgcn_mfma_f32_16x16x32_bf16(a[i], b[j], acc[i][j], 0, 0, 0);
    }
    #pragma unroll
    for (int i = 0; i < 4; i++)
        #pragma unroll
        for (int j = 0; j < 4; j++) {
            int col = n0 + wn + j * 16 + ls;
            float bv = bias ? bias[col] : 0.f;
            #pragma unroll
            for (int r = 0; r < 4; r++) {
                int row = m0 + wm + i * 16 + g * 4 + r;
                u16 val = f2bf(acc[i][j][r] + bv);
                if (xp_mode) {
                    int b_ = row >> 10, s_ = row & 1023;
                    int gate = col >> 9, u = col & 511;
                    int jj = u >> 5, uu = u & 31;
                    Cb[(((size_t)jj * 1024 + s_) * 16 + b_) * 128 + gate * 32 + uu] = val;
                } else {
                    Cb[(size_t)row * ldc + col] = val;
                }
            }
        }
}

// ---------------- fused attention: per (batch, 16-row q tile)
__global__ __launch_bounds__(256) void k_attn(const u16* __restrict__ qkv, const u16* __restrict__ vt,
                                              u16* __restrict__ attnO) {
    __shared__ u16 P[16 * 1024];
    __shared__ float mbuf[4][16], lbuf[4][16];
    int b = blockIdx.x >> 6, qt = blockIdx.x & 63;
    int q0 = qt * 16;
    int lane = threadIdx.x & 63, w = threadIdx.x >> 6;
    int ls = lane & 15, g = lane >> 4;
    const float sc = 0.04419417382f;  // 1/sqrt(512)

    f32x4 acc[16] = {};
    const u16* Qp = qkv + (size_t)(b * 1024 + q0 + ls) * 1536 + g * 8;
    const u16* Kp = qkv + (size_t)(b * 1024 + w * 256 + ls) * 1536 + 512 + g * 8;
    for (int k0 = 0; k0 < 512; k0 += 32) {
        bf16x8 a = ldfrag(Qp + k0);
        #pragma unroll
        for (int f = 0; f < 16; f++) {
            bf16x8 bb = ldfrag(Kp + (size_t)f * 16 * 1536 + k0);
            acc[f] = __builtin_amdgcn_mfma_f32_16x16x32_bf16(a, bb, acc[f], 0, 0, 0);
        }
    }
    float mx[4] = {-1e30f, -1e30f, -1e30f, -1e30f};
    #pragma unroll
    for (int f = 0; f < 16; f++)
        #pragma unroll
        for (int r = 0; r < 4; r++) mx[r] = fmaxf(mx[r], acc[f][r]);
    #pragma unroll
    for (int d = 1; d < 16; d <<= 1)
        #pragma unroll
        for (int r = 0; r < 4; r++) mx[r] = fmaxf(mx[r], __shfl_xor(mx[r], d, 64));
    if (ls == 0)
        #pragma unroll
        for (int r = 0; r < 4; r++) mbuf[w][g * 4 + r] = mx[r];
    __syncthreads();
    float m[4];
    #pragma unroll
    for (int r = 0; r < 4; r++) {
        int row = g * 4 + r;
        m[r] = fmaxf(fmaxf(mbuf[0][row], mbuf[1][row]), fmaxf(mbuf[2][row], mbuf[3][row])) * sc;
    }
    float sum[4] = {0.f, 0.f, 0.f, 0.f};
    #pragma unroll
    for (int f = 0; f < 16; f++)
        #pragma unroll
        for (int r = 0; r < 4; r++) {
            int row = g * 4 + r, col = w * 256 + f * 16 + ls;
            float e = __expf(acc[f][r] * sc - m[r]);
            sum[r] += e;
            P[(row * 1024 + col) ^ ((row & 7) << 3)] = f2bf(e);
        }
    #pragma unroll
    for (int d = 1; d < 16; d <<= 1)
        #pragma unroll
        for (int r = 0; r < 4; r++) sum[r] += __shfl_xor(sum[r], d, 64);
    if (ls == 0)
        #pragma unroll
        for (int r = 0; r < 4; r++) lbuf[w][g * 4 + r] = sum[r];
    __syncthreads();

    f32x4 o[8] = {};
    const bf16x8* Pv = reinterpret_cast<const bf16x8*>(P);
    const u16* Vp = vt + (size_t)b * 512 * 1024 + (size_t)(w * 128 + ls) * 1024 + g * 8;
    for (int k0 = 0; k0 < 1024; k0 += 32) {
        bf16x8 a = Pv[(ls * 128 + (k0 >> 3) + g) ^ (ls & 7)];
        #pragma unroll
        for (int q = 0; q < 8; q++) {
            bf16x8 bb = ldfrag(Vp + (size_t)q * 16 * 1024 + k0);
            o[q] = __builtin_amdgcn_mfma_f32_16x16x32_bf16(a, bb, o[q], 0, 0, 0);
        }
    }
    #pragma unroll
    for (int q = 0; q < 8; q++) {
        int col = w * 128 + q * 16 + ls;
        #pragma unroll
        for (int r = 0; r < 4; r++) {
            int row = g * 4 + r;
            float l = lbuf[0][row] + lbuf[1][row] + lbuf[2][row] + lbuf[3][row];
            attnO[(size_t)(b * 1024 + q0 + row) * 512 + col] = f2bf(o[q][r] / l);
        }
    }
}

// ---------------- proj Wo + residual(emb) + LayerNorm -> out1 (f32 + bf16)
__global__ __launch_bounds__(256) void k_projln(const u16* __restrict__ attnO, const u16* __restrict__ WoT,
                                                const float* __restrict__ emb, const float* __restrict__ gamma,
                                                const float* __restrict__ beta, float* __restrict__ out1f,
                                                u16* __restrict__ out1b) {
    __shared__ float buf[16][512];
    int m0 = blockIdx.x * 16;
    int lane = threadIdx.x & 63, w = threadIdx.x >> 6;
    int ls = lane & 15, g = lane >> 4;
    f32x4 acc[8] = {};
    const u16* Ap = attnO + (size_t)(m0 + ls) * 512 + g * 8;
    const u16* Bp = WoT + (size_t)(w * 128 + ls) * 512 + g * 8;
    for (int k0 = 0; k0 < 512; k0 += 32) {
        bf16x8 a = ldfrag(Ap + k0);
        #pragma unroll
        for (int q = 0; q < 8; q++) {
            bf16x8 bb = ldfrag(Bp + (size_t)q * 16 * 512 + k0);
            acc[q] = __builtin_amdgcn_mfma_f32_16x16x32_bf16(a, bb, acc[q], 0, 0, 0);
        }
    }
    #pragma unroll
    for (int q = 0; q < 8; q++) {
        int col = w * 128 + q * 16 + ls;
        #pragma unroll
        for (int r = 0; r < 4; r++) {
            int row = g * 4 + r;
            buf[row][col] = acc[q][r] + emb[(size_t)(m0 + row) * 512 + col];
        }
    }
    __syncthreads();
    int row = threadIdx.x >> 4, c0 = threadIdx.x & 15;
    float s = 0.f, s2 = 0.f;
    for (int c = c0; c < 512; c += 16) { float x = buf[row][c]; s += x; s2 += x * x; }
    #pragma unroll
    for (int d = 1; d < 16; d <<= 1) { s += __shfl_xor(s, d, 64); s2 += __shfl_xor(s2, d, 64); }
    float mu = s * (1.f / 512.f);
    float var = s2 * (1.f / 512.f) - mu * mu;
    float rs = rsqrtf(var + 1e-3f);
    for (int c = c0; c < 512; c += 16) {
        float y = gamma[c] * (buf[row][c] - mu) * rs + beta[c];
        out1f[(size_t)(m0 + row) * 512 + c] = y;
        out1b[(size_t)(m0 + row) * 512 + c] = f2bf(y);
    }
}

// ---------------- zero h0 slot + barrier counter
__global__ __launch_bounds__(256) void k_init2(u16* hbuf, int* bar) {
    int i = blockIdx.x * 256 + threadIdx.x;
    if (i < 8192) hbuf[i] = 0;
    if (i == 0) *bar = 0;
}

// ---------------- persistent LSTM scan: 16 blocks, all 1024 steps in-kernel.
// Block j owns u-cols [j*32, j*32+32) for all 4 gates; R-slice lives in VGPRs;
// c-state in registers; grid barrier = monotone atomic counter + threadfences.
__global__ __launch_bounds__(256) void k_lstm(const u16* __restrict__ xpp, const u16* __restrict__ rT,
                                              u16* hbuf /*2*16*512*/, float* __restrict__ hseq,
                                              int* bar) {
    int j = blockIdx.x;
    int tid = threadIdx.x;
    int lane = tid & 63, w = tid >> 6;
    int ls = lane & 15, g = lane >> 4;
    __shared__ float z[16][128];
    __shared__ u16 xb[2][2048];

    // R slice -> registers: wave w = gate w, cols j*32 + q*16+ls, k-octet kk*32+g*8
    bf16x8 rf[2][16];
    {
        const u16* Bp = rT + (size_t)(w * 512 + j * 32 + ls) * 512 + g * 8;
        #pragma unroll
        for (int q = 0; q < 2; q++)
            #pragma unroll
            for (int kk = 0; kk < 16; kk++)
                rf[q][kk] = ldfrag(Bp + (size_t)q * 16 * 512 + kk * 32);
    }
    float cA = 0.f, cB = 0.f;   // c-state for (it=0, it=1) lanes

    // prologue: xpp[s=0] -> xb[0]
    {
        uint4 v = *reinterpret_cast<const uint4*>(xpp + ((size_t)j * 1024) * 2048 + tid * 8);
        *reinterpret_cast<uint4*>(&xb[0][tid * 8]) = v;
    }
    __syncthreads();

    for (int s = 0; s < 1024; s++) {
        // prefetch next step's xp chunk (independent of h)
        uint4 nx;
        if (s + 1 < 1024)
            nx = *reinterpret_cast<const uint4*>(xpp + ((size_t)j * 1024 + s + 1) * 2048 + tid * 8);

        // z = h @ R  (A-frags from hbuf[s&1], all 4 waves share A)
        const u16* hp = hbuf + (s & 1) * 8192;
        f32x4 acc[2] = {};
        #pragma unroll
        for (int kk = 0; kk < 16; kk++) {
            bf16x8 a = ldfrag(hp + ls * 512 + kk * 32 + g * 8);
            acc[0] = __builtin_amdgcn_mfma_f32_16x16x32_bf16(a, rf[0][kk], acc[0], 0, 0, 0);
            acc[1] = __builtin_amdgcn_mfma_f32_16x16x32_bf16(a, rf[1][kk], acc[1], 0, 0, 0);
        }
        #pragma unroll
        for (int q = 0; q < 2; q++)
            #pragma unroll
            for (int r = 0; r < 4; r++)
                z[g * 4 + r][w * 32 + q * 16 + ls] = acc[q][r];
        __syncthreads();

        // gates: 512 (b,uu) pairs over 256 threads x2
        #pragma unroll
        for (int it = 0; it < 2; it++) {
            int idx = tid + it * 256;
            int b = idx >> 5, uu = idx & 31;
            const u16* xr = &xb[s & 1][b * 128];
            float zi = z[b][uu]      + bf2f(xr[uu]);
            float zf = z[b][32 + uu] + bf2f(xr[32 + uu]);
            float zg = z[b][64 + uu] + bf2f(xr[64 + uu]);
            float zo = z[b][96 + uu] + bf2f(xr[96 + uu]);
            float ii = 1.f / (1.f + __expf(-zi));
            float ff = 1.f / (1.f + __expf(-zf));
            float gg = fmaxf(zg, 0.f);
            float oo = 1.f / (1.f + __expf(-zo));
            float cp = it ? cB : cA;
            float cn = ff * cp + ii * gg;
            if (it) cB = cn; else cA = cn;
            float h = oo * fmaxf(cn, 0.f);
            hseq[((size_t)b * 1024 + s) * 512 + j * 32 + uu] = h;
            hbuf[((s + 1) & 1) * 8192 + b * 512 + j * 32 + uu] = f2bf(h);
        }
        if (s + 1 < 1024)
            *reinterpret_cast<uint4*>(&xb[(s + 1) & 1][tid * 8]) = nx;
        __syncthreads();   // all stores issued & complete, LDS reads done

        if (s + 1 < 1024) {
            if (tid == 0) {
                __threadfence();   // release: write back this XCD's dirty h lines
                __hip_atomic_fetch_add(bar, 1, __ATOMIC_RELEASE, __HIP_MEMORY_SCOPE_AGENT);
                int tgt = 16 * (s + 1);
                while (__hip_atomic_load(bar, __ATOMIC_RELAXED, __HIP_MEMORY_SCOPE_AGENT) < tgt)
                    __builtin_amdgcn_s_sleep(2);
            }
            __syncthreads();
            __threadfence();       // acquire: invalidate L1/L2 so remote h is visible
        }
    }
}

// ---------------- final LN in place on d_out: out = LN(d_out + out1f)
__global__ __launch_bounds__(256) void k_finln(float* __restrict__ io, const float* __restrict__ res,
                                               const float* __restrict__ gamma, const float* __restrict__ beta) {
    int m0 = blockIdx.x * 16;
    int row = threadIdx.x >> 4, c0 = threadIdx.x & 15;
    size_t base = (size_t)(m0 + row) * 512;
    float x[32];
    float s = 0.f, s2 = 0.f;
    #pragma unroll
    for (int i = 0; i < 32; i++) {
        int cc = c0 + i * 16;
        x[i] = io[base + cc] + res[base + cc];
        s += x[i]; s2 += x[i] * x[i];
    }
    #pragma unroll
    for (int d = 1; d < 16; d <<= 1) { s += __shfl_xor(s, d, 64); s2 += __shfl_xor(s2, d, 64); }
    float mu = s * (1.f / 512.f);
    float var = s2 * (1.f / 512.f) - mu * mu;
    float rs = rsqrtf(var + 1e-3f);
    #pragma unroll
    for (int i = 0; i < 32; i++) {
        int cc = c0 + i * 16;
        io[base + cc] = gamma[cc] * (x[i] - mu) * rs + beta[cc];
    }
}

extern "C" void kernel_launch(void* const* d_in, const int* in_sizes, int n_in,
                              void* d_out, int out_size, void* d_ws, size_t ws_size,
                              hipStream_t stream) {
    (void)in_sizes; (void)n_in; (void)out_size; (void)ws_size;
    const float* emb   = (const float*)d_in[0];
    const float* Wq    = (const float*)d_in[1];
    const float* Wk    = (const float*)d_in[2];
    const float* Wv    = (const float*)d_in[3];
    const float* Wo    = (const float*)d_in[4];
    const float* gamma = (const float*)d_in[5];
    const float* beta  = (const float*)d_in[6];
    const float* lk    = (const float*)d_in[7];
    const float* lr    = (const float*)d_in[8];
    const float* lb    = (const float*)d_in[9];

    char* w = (char*)d_ws;
    size_t o = 0;
    u16* WqkvT = (u16*)(w + o); o += (size_t)1536 * 512 * 2;
    u16* WoT   = (u16*)(w + o); o += (size_t)512 * 512 * 2;
    u16* kT    = (u16*)(w + o); o += (size_t)2048 * 512 * 2;
    u16* rT    = (u16*)(w + o); o += (size_t)2048 * 512 * 2;
    u16* Xbf   = (u16*)(w + o); o += (size_t)16384 * 512 * 2;     // reused as attnO
    u16* QKV   = (u16*)(w + o); o += (size_t)16384 * 1536 * 2;    // reused (with Vt) as xpp
    u16* Vt    = (u16*)(w + o); o += (size_t)16 * 512 * 1024 * 2;
    float* out1f = (float*)(w + o); o += (size_t)16384 * 512 * 4;
    u16* out1b = (u16*)(w + o); o += (size_t)16384 * 512 * 2;
    u16* hbuf  = (u16*)(w + o); o += (size_t)2 * 16 * 512 * 2;
    int* bar   = (int*)(w + o);  o += 256;
    u16* attnO = Xbf;   // Xbf dead after QKV GEMM
    u16* xpp   = QKV;   // QKV+Vt dead after attention; 67.1 MB available >= 64 MB
    float* outp = (float*)d_out;

    k_cvt<<<8192, 256, 0, stream>>>(emb, Xbf, 16384 * 512);
    k_tr_f2b<<<dim3(16, 16), 256, 0, stream>>>(Wq, WqkvT, 512, 512);
    k_tr_f2b<<<dim3(16, 16), 256, 0, stream>>>(Wk, WqkvT + 512 * 512, 512, 512);
    k_tr_f2b<<<dim3(16, 16), 256, 0, stream>>>(Wv, WqkvT + 1024 * 512, 512, 512);
    k_tr_f2b<<<dim3(16, 16), 256, 0, stream>>>(Wo, WoT, 512, 512);
    k_tr_f2b<<<dim3(64, 16), 256, 0, stream>>>(lk, kT, 512, 2048);
    k_tr_f2b<<<dim3(64, 16), 256, 0, stream>>>(lr, rT, 512, 2048);
    k_gemm<<<128 * 12, 256, 0, stream>>>(Xbf, WqkvT, QKV, nullptr, 16384, 1536, 512, 1536, 0);
    k_tr_v<<<dim3(32, 16, 16), 256, 0, stream>>>(QKV, Vt);
    k_attn<<<1024, 256, 0, stream>>>(QKV, Vt, attnO);
    k_projln<<<1024, 256, 0, stream>>>(attnO, WoT, emb, gamma, beta, out1f, out1b);
    k_gemm<<<128 * 16, 256, 0, stream>>>(out1b, kT, xpp, lb, 16384, 2048, 512, 2048, 1);
    k_init2<<<32, 256, 0, stream>>>(hbuf, bar);
    k_lstm<<<16, 256, 0, stream>>>(xpp, rT, hbuf, outp, bar);
    k_finln<<<1024, 256, 0, stream>>>(outp, out1f, gamma, beta);
}

// Round 4
// 5376.680 us; speedup vs baseline: 1.5521x; 1.1516x over previous
//
#include <hip/hip_runtime.h>

typedef unsigned short u16;
typedef unsigned int   u32;
typedef unsigned long long ull;
typedef __attribute__((ext_vector_type(8))) __bf16 bf16x8;
typedef __attribute__((ext_vector_type(4))) float  f32x4;

#define DEV static __device__ __forceinline__

DEV u16 f2bf(float f) {
    u32 u = __float_as_uint(f);
    u = (u + 0x7fffu + ((u >> 16) & 1u)) >> 16;
    return (u16)u;
}
DEV float bf2f(u16 b) { return __uint_as_float(((u32)b) << 16); }
DEV bf16x8 ldfrag(const u16* p) { return *reinterpret_cast<const bf16x8*>(p); }

// ---------------------------------------------------------------- cvt f32->bf16
__global__ __launch_bounds__(256) void k_cvt(const float* __restrict__ in, u16* __restrict__ out, int n) {
    int i = (blockIdx.x * 256 + threadIdx.x) * 4;
    if (i < n) {
        float4 v = *reinterpret_cast<const float4*>(in + i);
        ushort4 o; o.x = f2bf(v.x); o.y = f2bf(v.y); o.z = f2bf(v.z); o.w = f2bf(v.w);
        *reinterpret_cast<ushort4*>(out + i) = o;
    }
}

// ------------------------------------------- transpose f32 in[R][C] -> bf16 out[C][R]
__global__ __launch_bounds__(256) void k_tr_f2b(const float* __restrict__ in, u16* __restrict__ out,
                                                int R, int C) {
    __shared__ float t[32][33];
    int c0 = blockIdx.x * 32, r0 = blockIdx.y * 32;
    int tx = threadIdx.x % 32, ty = threadIdx.x / 32;   // ty 0..7
    for (int i = 0; i < 32; i += 8)
        t[ty + i][tx] = in[(r0 + ty + i) * C + c0 + tx];
    __syncthreads();
    for (int i = 0; i < 32; i += 8)
        out[(size_t)(c0 + ty + i) * R + r0 + tx] = f2bf(t[tx][ty + i]);
}

// ---------------- transpose V (cols 1024..1535 of QKV) -> Vt[b][h][s] (bf16)
__global__ __launch_bounds__(256) void k_tr_v(const u16* __restrict__ qkv, u16* __restrict__ vt) {
    __shared__ u16 t[32][33];
    int b = blockIdx.z;
    int s0 = blockIdx.x * 32, h0 = blockIdx.y * 32;
    int tx = threadIdx.x % 32, ty = threadIdx.x / 32;
    for (int i = 0; i < 32; i += 8)
        t[ty + i][tx] = qkv[(size_t)(b * 1024 + s0 + ty + i) * 1536 + 1024 + h0 + tx];
    __syncthreads();
    for (int i = 0; i < 32; i += 8)
        vt[(size_t)b * 512 * 1024 + (size_t)(h0 + ty + i) * 1024 + s0 + tx] = t[tx][ty + i];
}

// ---------------- generic bf16 GEMM: C[M,N] = A[M,K] * Bt[N,K]^T (+bias), bf16 out
// xp_mode: remap store to per-block LSTM layout xpp[j][s][b][gate][uu]
__global__ __launch_bounds__(256) void k_gemm(const u16* __restrict__ A, const u16* __restrict__ Bt,
                                              u16* __restrict__ Cb, const float* __restrict__ bias,
                                              int M, int N, int K, int ldc, int xp_mode) {
    int mtiles = M >> 7;
    int mt = blockIdx.x % mtiles, nt = blockIdx.x / mtiles;
    int m0 = mt << 7, n0 = nt << 7;
    int lane = threadIdx.x & 63, wid = threadIdx.x >> 6;
    int wm = (wid >> 1) * 64, wn = (wid & 1) * 64;
    int ls = lane & 15, g = lane >> 4;
    f32x4 acc[4][4] = {};
    const u16* Ap = A + (size_t)(m0 + wm + ls) * K + g * 8;
    const u16* Bp = Bt + (size_t)(n0 + wn + ls) * K + g * 8;
    for (int k0 = 0; k0 < K; k0 += 32) {
        bf16x8 a[4], b[4];
        #pragma unroll
        for (int i = 0; i < 4; i++) a[i] = ldfrag(Ap + (size_t)i * 16 * K + k0);
        #pragma unroll
        for (int j = 0; j < 4; j++) b[j] = ldfrag(Bp + (size_t)j * 16 * K + k0);
        #pragma unroll
        for (int i = 0; i < 4; i++)
            #pragma unroll
            for (int j = 0; j < 4; j++)
                acc[i][j] = __builtin_amdgcn_mfma_f32_16x16x32_bf16(a[i], b[j], acc[i][j], 0, 0, 0);
    }
    #pragma unroll
    for (int i = 0; i < 4; i++)
        #pragma unroll
        for (int j = 0; j < 4; j++) {
            int col = n0 + wn + j * 16 + ls;
            float bv = bias ? bias[col] : 0.f;
            #pragma unroll
            for (int r = 0; r < 4; r++) {
                int row = m0 + wm + i * 16 + g * 4 + r;
                u16 val = f2bf(acc[i][j][r] + bv);
                if (xp_mode) {
                    int b_ = row >> 10, s_ = row & 1023;
                    int gate = col >> 9, u = col & 511;
                    int jj = u >> 5, uu = u & 31;
                    Cb[(((size_t)jj * 1024 + s_) * 16 + b_) * 128 + gate * 32 + uu] = val;
                } else {
                    Cb[(size_t)row * ldc + col] = val;
                }
            }
        }
}

// ---------------- fused attention: per (batch, 16-row q tile)
__global__ __launch_bounds__(256) void k_attn(const u16* __restrict__ qkv, const u16* __restrict__ vt,
                                              u16* __restrict__ attnO) {
    __shared__ u16 P[16 * 1024];
    __shared__ float mbuf[4][16], lbuf[4][16];
    int b = blockIdx.x >> 6, qt = blockIdx.x & 63;
    int q0 = qt * 16;
    int lane = threadIdx.x & 63, w = threadIdx.x >> 6;
    int ls = lane & 15, g = lane >> 4;
    const float sc = 0.04419417382f;  // 1/sqrt(512)

    f32x4 acc[16] = {};
    const u16* Qp = qkv + (size_t)(b * 1024 + q0 + ls) * 1536 + g * 8;
    const u16* Kp = qkv + (size_t)(b * 1024 + w * 256 + ls) * 1536 + 512 + g * 8;
    for (int k0 = 0; k0 < 512; k0 += 32) {
        bf16x8 a = ldfrag(Qp + k0);
        #pragma unroll
        for (int f = 0; f < 16; f++) {
            bf16x8 bb = ldfrag(Kp + (size_t)f * 16 * 1536 + k0);
            acc[f] = __builtin_amdgcn_mfma_f32_16x16x32_bf16(a, bb, acc[f], 0, 0, 0);
        }
    }
    float mx[4] = {-1e30f, -1e30f, -1e30f, -1e30f};
    #pragma unroll
    for (int f = 0; f < 16; f++)
        #pragma unroll
        for (int r = 0; r < 4; r++) mx[r] = fmaxf(mx[r], acc[f][r]);
    #pragma unroll
    for (int d = 1; d < 16; d <<= 1)
        #pragma unroll
        for (int r = 0; r < 4; r++) mx[r] = fmaxf(mx[r], __shfl_xor(mx[r], d, 64));
    if (ls == 0)
        #pragma unroll
        for (int r = 0; r < 4; r++) mbuf[w][g * 4 + r] = mx[r];
    __syncthreads();
    float m[4];
    #pragma unroll
    for (int r = 0; r < 4; r++) {
        int row = g * 4 + r;
        m[r] = fmaxf(fmaxf(mbuf[0][row], mbuf[1][row]), fmaxf(mbuf[2][row], mbuf[3][row])) * sc;
    }
    float sum[4] = {0.f, 0.f, 0.f, 0.f};
    #pragma unroll
    for (int f = 0; f < 16; f++)
        #pragma unroll
        for (int r = 0; r < 4; r++) {
            int row = g * 4 + r, col = w * 256 + f * 16 + ls;
            float e = __expf(acc[f][r] * sc - m[r]);
            sum[r] += e;
            P[(row * 1024 + col) ^ ((row & 7) << 3)] = f2bf(e);
        }
    #pragma unroll
    for (int d = 1; d < 16; d <<= 1)
        #pragma unroll
        for (int r = 0; r < 4; r++) sum[r] += __shfl_xor(sum[r], d, 64);
    if (ls == 0)
        #pragma unroll
        for (int r = 0; r < 4; r++) lbuf[w][g * 4 + r] = sum[r];
    __syncthreads();

    f32x4 o[8] = {};
    const bf16x8* Pv = reinterpret_cast<const bf16x8*>(P);
    const u16* Vp = vt + (size_t)b * 512 * 1024 + (size_t)(w * 128 + ls) * 1024 + g * 8;
    for (int k0 = 0; k0 < 1024; k0 += 32) {
        bf16x8 a = Pv[(ls * 128 + (k0 >> 3) + g) ^ (ls & 7)];
        #pragma unroll
        for (int q = 0; q < 8; q++) {
            bf16x8 bb = ldfrag(Vp + (size_t)q * 16 * 1024 + k0);
            o[q] = __builtin_amdgcn_mfma_f32_16x16x32_bf16(a, bb, o[q], 0, 0, 0);
        }
    }
    #pragma unroll
    for (int q = 0; q < 8; q++) {
        int col = w * 128 + q * 16 + ls;
        #pragma unroll
        for (int r = 0; r < 4; r++) {
            int row = g * 4 + r;
            float l = lbuf[0][row] + lbuf[1][row] + lbuf[2][row] + lbuf[3][row];
            attnO[(size_t)(b * 1024 + q0 + row) * 512 + col] = f2bf(o[q][r] / l);
        }
    }
}

// ---------------- proj Wo + residual(emb) + LayerNorm -> out1 (f32 + bf16)
__global__ __launch_bounds__(256) void k_projln(const u16* __restrict__ attnO, const u16* __restrict__ WoT,
                                                const float* __restrict__ emb, const float* __restrict__ gamma,
                                                const float* __restrict__ beta, float* __restrict__ out1f,
                                                u16* __restrict__ out1b) {
    __shared__ float buf[16][512];
    int m0 = blockIdx.x * 16;
    int lane = threadIdx.x & 63, w = threadIdx.x >> 6;
    int ls = lane & 15, g = lane >> 4;
    f32x4 acc[8] = {};
    const u16* Ap = attnO + (size_t)(m0 + ls) * 512 + g * 8;
    const u16* Bp = WoT + (size_t)(w * 128 + ls) * 512 + g * 8;
    for (int k0 = 0; k0 < 512; k0 += 32) {
        bf16x8 a = ldfrag(Ap + k0);
        #pragma unroll
        for (int q = 0; q < 8; q++) {
            bf16x8 bb = ldfrag(Bp + (size_t)q * 16 * 512 + k0);
            acc[q] = __builtin_amdgcn_mfma_f32_16x16x32_bf16(a, bb, acc[q], 0, 0, 0);
        }
    }
    #pragma unroll
    for (int q = 0; q < 8; q++) {
        int col = w * 128 + q * 16 + ls;
        #pragma unroll
        for (int r = 0; r < 4; r++) {
            int row = g * 4 + r;
            buf[row][col] = acc[q][r] + emb[(size_t)(m0 + row) * 512 + col];
        }
    }
    __syncthreads();
    int row = threadIdx.x >> 4, c0 = threadIdx.x & 15;
    float s = 0.f, s2 = 0.f;
    for (int c = c0; c < 512; c += 16) { float x = buf[row][c]; s += x; s2 += x * x; }
    #pragma unroll
    for (int d = 1; d < 16; d <<= 1) { s += __shfl_xor(s, d, 64); s2 += __shfl_xor(s2, d, 64); }
    float mu = s * (1.f / 512.f);
    float var = s2 * (1.f / 512.f) - mu * mu;
    float rs = rsqrtf(var + 1e-3f);
    for (int c = c0; c < 512; c += 16) {
        float y = gamma[c] * (buf[row][c] - mu) * rs + beta[c];
        out1f[(size_t)(m0 + row) * 512 + c] = y;
        out1b[(size_t)(m0 + row) * 512 + c] = f2bf(y);
    }
}

// ---------------- zero step counters
__global__ __launch_bounds__(256) void k_init2(u32* cnt) {
    int i = blockIdx.x * 256 + threadIdx.x;
    if (i < 1024 * 16) cnt[i] = 0;
}

// ---------------- persistent LSTM scan: 16 blocks, all 1024 steps in-kernel.
// h exchange via relaxed agent-scope atomics (coherent at LLC, no cache
// maintenance fences); per-step sync = vmcnt(0) + one fetch_add + poll.
__global__ __launch_bounds__(256) void k_lstm(const u16* __restrict__ xpp, const u16* __restrict__ rT,
                                              void* hbufv, float* __restrict__ hseq, u32* cnt) {
    int j = blockIdx.x;
    int tid = threadIdx.x;
    int lane = tid & 63, w = tid >> 6;
    int ls = lane & 15, g = lane >> 4;
    u32* hbG32 = (u32*)hbufv;
    ull* hbG64 = (ull*)hbufv;
    __shared__ float z[16][128];
    __shared__ u16 hb[8192];       // h[16][512], XOR-swizzled: byte ^= (row&7)<<4
    __shared__ u16 xb[2][2048];

    // R slice -> registers: wave w = gate w, cols j*32 + q*16+ls, k-octet kk*32+g*8
    bf16x8 rf[2][16];
    {
        const u16* Bp = rT + (size_t)(w * 512 + j * 32 + ls) * 512 + g * 8;
        #pragma unroll
        for (int q = 0; q < 2; q++)
            #pragma unroll
            for (int kk = 0; kk < 16; kk++)
                rf[q][kk] = ldfrag(Bp + (size_t)q * 16 * 512 + kk * 32);
    }
    float cA = 0.f, cB = 0.f;   // c-state for this thread's two (b,uu) pairs

    // h0 = 0 (built locally, no global round-trip)
    for (int i = tid; i < 4096; i += 256) ((u32*)hb)[i] = 0;
    // prologue: xpp[s=0] -> xb[0]
    {
        uint4 v = *reinterpret_cast<const uint4*>(xpp + ((size_t)j * 1024) * 2048 + tid * 8);
        *reinterpret_cast<uint4*>(&xb[0][tid * 8]) = v;
    }
    __syncthreads();

    for (int s = 0; s < 1024; s++) {
        // prefetch next step's xp chunk (independent of h)
        uint4 nx;
        if (s + 1 < 1024)
            nx = *reinterpret_cast<const uint4*>(xpp + ((size_t)j * 1024 + s + 1) * 2048 + tid * 8);

        // z = h @ R  (A-frags from swizzled LDS hb)
        f32x4 acc[2] = {};
        #pragma unroll
        for (int kk = 0; kk < 16; kk++) {
            int aidx = (ls * 512 + kk * 32 + g * 8) ^ ((ls & 7) << 3);
            bf16x8 a = ldfrag(&hb[aidx]);
            acc[0] = __builtin_amdgcn_mfma_f32_16x16x32_bf16(a, rf[0][kk], acc[0], 0, 0, 0);
            acc[1] = __builtin_amdgcn_mfma_f32_16x16x32_bf16(a, rf[1][kk], acc[1], 0, 0, 0);
        }
        #pragma unroll
        for (int q = 0; q < 2; q++)
            #pragma unroll
            for (int r = 0; r < 4; r++)
                z[g * 4 + r][w * 32 + q * 16 + ls] = acc[q][r];
        __syncthreads();

        // gates: thread t -> batch b = t>>4, uu pair (uu0, uu0+1)
        {
            int b = tid >> 4, uu0 = (tid & 15) * 2;
            const u16* xr = &xb[s & 1][b * 128];
            float hres[2];
            #pragma unroll
            for (int p = 0; p < 2; p++) {
                int uu = uu0 + p;
                float zi = z[b][uu]      + bf2f(xr[uu]);
                float zf = z[b][32 + uu] + bf2f(xr[32 + uu]);
                float zg = z[b][64 + uu] + bf2f(xr[64 + uu]);
                float zo = z[b][96 + uu] + bf2f(xr[96 + uu]);
                float ii = 1.f / (1.f + __expf(-zi));
                float ff = 1.f / (1.f + __expf(-zf));
                float gg = fmaxf(zg, 0.f);
                float oo = 1.f / (1.f + __expf(-zo));
                float cp = p ? cB : cA;
                float cn = ff * cp + ii * gg;
                if (p) cB = cn; else cA = cn;
                hres[p] = oo * fmaxf(cn, 0.f);
            }
            *reinterpret_cast<float2*>(&hseq[((size_t)b * 1024 + s) * 512 + j * 32 + uu0]) =
                make_float2(hres[0], hres[1]);
            u32 packed = (u32)f2bf(hres[0]) | ((u32)f2bf(hres[1]) << 16);
            __hip_atomic_store(hbG32 + ((s + 1) & 1) * 4096 + b * 256 + ((j * 32 + uu0) >> 1),
                               packed, __ATOMIC_RELAXED, __HIP_MEMORY_SCOPE_AGENT);
        }
        if (s + 1 < 1024)
            *reinterpret_cast<uint4*>(&xb[(s + 1) & 1][tid * 8]) = nx;

        // drain coherent stores, then signal + wait + refill
        asm volatile("s_waitcnt vmcnt(0)" ::: "memory");
        __syncthreads();   // all waves' h stores globally visible; LDS reads of z/hb done
        if (s + 1 < 1024) {
            u32* c = cnt + s * 16;   // 64B-spread counter lines
            if (tid == 0)
                __hip_atomic_fetch_add(c, 1u, __ATOMIC_RELAXED, __HIP_MEMORY_SCOPE_AGENT);
            while (__hip_atomic_load(c, __ATOMIC_RELAXED, __HIP_MEMORY_SCOPE_AGENT) < 16u)
                __builtin_amdgcn_s_sleep(1);
            asm volatile("" ::: "memory");
            // refill hb from coherent hbuf slot (s+1)&1 (2048 u64 per slot), swizzled
            const ull* src = hbG64 + ((s + 1) & 1) * 2048;
            #pragma unroll
            for (int i = 0; i < 8; i++) {
                int li = i * 256 + tid;           // coalesced: lanes -> consecutive u64
                int row = li >> 7;
                ((ull*)hb)[li ^ ((row & 7) << 1)] =
                    __hip_atomic_load(src + li, __ATOMIC_RELAXED, __HIP_MEMORY_SCOPE_AGENT);
            }
            __syncthreads();
        }
    }
}

// ---------------- final LN in place on d_out: out = LN(d_out + out1f)
__global__ __launch_bounds__(256) void k_finln(float* __restrict__ io, const float* __restrict__ res,
                                               const float* __restrict__ gamma, const float* __restrict__ beta) {
    int m0 = blockIdx.x * 16;
    int row = threadIdx.x >> 4, c0 = threadIdx.x & 15;
    size_t base = (size_t)(m0 + row) * 512;
    float x[32];
    float s = 0.f, s2 = 0.f;
    #pragma unroll
    for (int i = 0; i < 32; i++) {
        int cc = c0 + i * 16;
        x[i] = io[base + cc] + res[base + cc];
        s += x[i]; s2 += x[i] * x[i];
    }
    #pragma unroll
    for (int d = 1; d < 16; d <<= 1) { s += __shfl_xor(s, d, 64); s2 += __shfl_xor(s2, d, 64); }
    float mu = s * (1.f / 512.f);
    float var = s2 * (1.f / 512.f) - mu * mu;
    float rs = rsqrtf(var + 1e-3f);
    #pragma unroll
    for (int i = 0; i < 32; i++) {
        int cc = c0 + i * 16;
        io[base + cc] = gamma[cc] * (x[i] - mu) * rs + beta[cc];
    }
}

extern "C" void kernel_launch(void* const* d_in, const int* in_sizes, int n_in,
                              void* d_out, int out_size, void* d_ws, size_t ws_size,
                              hipStream_t stream) {
    (void)in_sizes; (void)n_in; (void)out_size; (void)ws_size;
    const float* emb   = (const float*)d_in[0];
    const float* Wq    = (const float*)d_in[1];
    const float* Wk    = (const float*)d_in[2];
    const float* Wv    = (const float*)d_in[3];
    const float* Wo    = (const float*)d_in[4];
    const float* gamma = (const float*)d_in[5];
    const float* beta  = (const float*)d_in[6];
    const float* lk    = (const float*)d_in[7];
    const float* lr    = (const float*)d_in[8];
    const float* lb    = (const float*)d_in[9];

    char* w = (char*)d_ws;
    size_t o = 0;
    u16* WqkvT = (u16*)(w + o); o += (size_t)1536 * 512 * 2;
    u16* WoT   = (u16*)(w + o); o += (size_t)512 * 512 * 2;
    u16* kT    = (u16*)(w + o); o += (size_t)2048 * 512 * 2;
    u16* rT    = (u16*)(w + o); o += (size_t)2048 * 512 * 2;
    u16* Xbf   = (u16*)(w + o); o += (size_t)16384 * 512 * 2;     // reused as attnO
    u16* QKV   = (u16*)(w + o); o += (size_t)16384 * 1536 * 2;    // reused (with Vt) as xpp
    u16* Vt    = (u16*)(w + o); o += (size_t)16 * 512 * 1024 * 2;
    float* out1f = (float*)(w + o); o += (size_t)16384 * 512 * 4;
    u16* out1b = (u16*)(w + o); o += (size_t)16384 * 512 * 2;
    void* hbuf = (void*)(w + o); o += (size_t)2 * 16 * 512 * 2;
    u32* cnt   = (u32*)(w + o);  o += (size_t)1024 * 16 * 4;
    u16* attnO = Xbf;   // Xbf dead after QKV GEMM
    u16* xpp   = QKV;   // QKV+Vt dead after attention
    float* outp = (float*)d_out;

    k_cvt<<<8192, 256, 0, stream>>>(emb, Xbf, 16384 * 512);
    k_tr_f2b<<<dim3(16, 16), 256, 0, stream>>>(Wq, WqkvT, 512, 512);
    k_tr_f2b<<<dim3(16, 16), 256, 0, stream>>>(Wk, WqkvT + 512 * 512, 512, 512);
    k_tr_f2b<<<dim3(16, 16), 256, 0, stream>>>(Wv, WqkvT + 1024 * 512, 512, 512);
    k_tr_f2b<<<dim3(16, 16), 256, 0, stream>>>(Wo, WoT, 512, 512);
    k_tr_f2b<<<dim3(64, 16), 256, 0, stream>>>(lk, kT, 512, 2048);
    k_tr_f2b<<<dim3(64, 16), 256, 0, stream>>>(lr, rT, 512, 2048);
    k_gemm<<<128 * 12, 256, 0, stream>>>(Xbf, WqkvT, QKV, nullptr, 16384, 1536, 512, 1536, 0);
    k_tr_v<<<dim3(32, 16, 16), 256, 0, stream>>>(QKV, Vt);
    k_attn<<<1024, 256, 0, stream>>>(QKV, Vt, attnO);
    k_projln<<<1024, 256, 0, stream>>>(attnO, WoT, emb, gamma, beta, out1f, out1b);
    k_gemm<<<128 * 16, 256, 0, stream>>>(out1b, kT, xpp, lb, 16384, 2048, 512, 2048, 1);
    k_init2<<<64, 256, 0, stream>>>(cnt);
    k_lstm<<<16, 256, 0, stream>>>(xpp, rT, hbuf, outp, cnt);
    k_finln<<<1024, 256, 0, stream>>>(outp, out1f, gamma, beta);
}

// Round 5
// 4785.021 us; speedup vs baseline: 1.7440x; 1.1236x over previous
//
#include <hip/hip_runtime.h>

typedef unsigned short u16;
typedef unsigned int   u32;
typedef unsigned long long ull;
typedef __attribute__((ext_vector_type(8))) __bf16 bf16x8;
typedef __attribute__((ext_vector_type(4))) float  f32x4;

#define DEV static __device__ __forceinline__

DEV u16 f2bf(float f) {
    u32 u = __float_as_uint(f);
    u = (u + 0x7fffu + ((u >> 16) & 1u)) >> 16;
    return (u16)u;
}
DEV float bf2f(u16 b) { return __uint_as_float(((u32)b) << 16); }
DEV bf16x8 ldfrag(const u16* p) { return *reinterpret_cast<const bf16x8*>(p); }

// ---------------------------------------------------------------- cvt f32->bf16
__global__ __launch_bounds__(256) void k_cvt(const float* __restrict__ in, u16* __restrict__ out, int n) {
    int i = (blockIdx.x * 256 + threadIdx.x) * 4;
    if (i < n) {
        float4 v = *reinterpret_cast<const float4*>(in + i);
        ushort4 o; o.x = f2bf(v.x); o.y = f2bf(v.y); o.z = f2bf(v.z); o.w = f2bf(v.w);
        *reinterpret_cast<ushort4*>(out + i) = o;
    }
}

// ------------------------------------------- transpose f32 in[R][C] -> bf16 out[C][R]
__global__ __launch_bounds__(256) void k_tr_f2b(const float* __restrict__ in, u16* __restrict__ out,
                                                int R, int C) {
    __shared__ float t[32][33];
    int c0 = blockIdx.x * 32, r0 = blockIdx.y * 32;
    int tx = threadIdx.x % 32, ty = threadIdx.x / 32;   // ty 0..7
    for (int i = 0; i < 32; i += 8)
        t[ty + i][tx] = in[(r0 + ty + i) * C + c0 + tx];
    __syncthreads();
    for (int i = 0; i < 32; i += 8)
        out[(size_t)(c0 + ty + i) * R + r0 + tx] = f2bf(t[tx][ty + i]);
}

// ---------------- transpose V (cols 1024..1535 of QKV) -> Vt[b][h][s] (bf16)
__global__ __launch_bounds__(256) void k_tr_v(const u16* __restrict__ qkv, u16* __restrict__ vt) {
    __shared__ u16 t[32][33];
    int b = blockIdx.z;
    int s0 = blockIdx.x * 32, h0 = blockIdx.y * 32;
    int tx = threadIdx.x % 32, ty = threadIdx.x / 32;
    for (int i = 0; i < 32; i += 8)
        t[ty + i][tx] = qkv[(size_t)(b * 1024 + s0 + ty + i) * 1536 + 1024 + h0 + tx];
    __syncthreads();
    for (int i = 0; i < 32; i += 8)
        vt[(size_t)b * 512 * 1024 + (size_t)(h0 + ty + i) * 1024 + s0 + tx] = t[tx][ty + i];
}

// ---------------- generic bf16 GEMM: C[M,N] = A[M,K] * Bt[N,K]^T (+bias), bf16 out
// xp_mode: remap store to per-block LSTM layout xpp[j][s][b][gate][uu]
__global__ __launch_bounds__(256) void k_gemm(const u16* __restrict__ A, const u16* __restrict__ Bt,
                                              u16* __restrict__ Cb, const float* __restrict__ bias,
                                              int M, int N, int K, int ldc, int xp_mode) {
    int mtiles = M >> 7;
    int mt = blockIdx.x % mtiles, nt = blockIdx.x / mtiles;
    int m0 = mt << 7, n0 = nt << 7;
    int lane = threadIdx.x & 63, wid = threadIdx.x >> 6;
    int wm = (wid >> 1) * 64, wn = (wid & 1) * 64;
    int ls = lane & 15, g = lane >> 4;
    f32x4 acc[4][4] = {};
    const u16* Ap = A + (size_t)(m0 + wm + ls) * K + g * 8;
    const u16* Bp = Bt + (size_t)(n0 + wn + ls) * K + g * 8;
    for (int k0 = 0; k0 < K; k0 += 32) {
        bf16x8 a[4], b[4];
        #pragma unroll
        for (int i = 0; i < 4; i++) a[i] = ldfrag(Ap + (size_t)i * 16 * K + k0);
        #pragma unroll
        for (int j = 0; j < 4; j++) b[j] = ldfrag(Bp + (size_t)j * 16 * K + k0);
        #pragma unroll
        for (int i = 0; i < 4; i++)
            #pragma unroll
            for (int j = 0; j < 4; j++)
                acc[i][j] = __builtin_amdgcn_mfma_f32_16x16x32_bf16(a[i], b[j], acc[i][j], 0, 0, 0);
    }
    #pragma unroll
    for (int i = 0; i < 4; i++)
        #pragma unroll
        for (int j = 0; j < 4; j++) {
            int col = n0 + wn + j * 16 + ls;
            float bv = bias ? bias[col] : 0.f;
            #pragma unroll
            for (int r = 0; r < 4; r++) {
                int row = m0 + wm + i * 16 + g * 4 + r;
                u16 val = f2bf(acc[i][j][r] + bv);
                if (xp_mode) {
                    int b_ = row >> 10, s_ = row & 1023;
                    int gate = col >> 9, u = col & 511;
                    int jj = u >> 5, uu = u & 31;
                    Cb[(((size_t)jj * 1024 + s_) * 16 + b_) * 128 + gate * 32 + uu] = val;
                } else {
                    Cb[(size_t)row * ldc + col] = val;
                }
            }
        }
}

// ---------------- fused attention: per (batch, 16-row q tile)
__global__ __launch_bounds__(256) void k_attn(const u16* __restrict__ qkv, const u16* __restrict__ vt,
                                              u16* __restrict__ attnO) {
    __shared__ u16 P[16 * 1024];
    __shared__ float mbuf[4][16], lbuf[4][16];
    int b = blockIdx.x >> 6, qt = blockIdx.x & 63;
    int q0 = qt * 16;
    int lane = threadIdx.x & 63, w = threadIdx.x >> 6;
    int ls = lane & 15, g = lane >> 4;
    const float sc = 0.04419417382f;  // 1/sqrt(512)

    f32x4 acc[16] = {};
    const u16* Qp = qkv + (size_t)(b * 1024 + q0 + ls) * 1536 + g * 8;
    const u16* Kp = qkv + (size_t)(b * 1024 + w * 256 + ls) * 1536 + 512 + g * 8;
    for (int k0 = 0; k0 < 512; k0 += 32) {
        bf16x8 a = ldfrag(Qp + k0);
        #pragma unroll
        for (int f = 0; f < 16; f++) {
            bf16x8 bb = ldfrag(Kp + (size_t)f * 16 * 1536 + k0);
            acc[f] = __builtin_amdgcn_mfma_f32_16x16x32_bf16(a, bb, acc[f], 0, 0, 0);
        }
    }
    float mx[4] = {-1e30f, -1e30f, -1e30f, -1e30f};
    #pragma unroll
    for (int f = 0; f < 16; f++)
        #pragma unroll
        for (int r = 0; r < 4; r++) mx[r] = fmaxf(mx[r], acc[f][r]);
    #pragma unroll
    for (int d = 1; d < 16; d <<= 1)
        #pragma unroll
        for (int r = 0; r < 4; r++) mx[r] = fmaxf(mx[r], __shfl_xor(mx[r], d, 64));
    if (ls == 0)
        #pragma unroll
        for (int r = 0; r < 4; r++) mbuf[w][g * 4 + r] = mx[r];
    __syncthreads();
    float m[4];
    #pragma unroll
    for (int r = 0; r < 4; r++) {
        int row = g * 4 + r;
        m[r] = fmaxf(fmaxf(mbuf[0][row], mbuf[1][row]), fmaxf(mbuf[2][row], mbuf[3][row])) * sc;
    }
    float sum[4] = {0.f, 0.f, 0.f, 0.f};
    #pragma unroll
    for (int f = 0; f < 16; f++)
        #pragma unroll
        for (int r = 0; r < 4; r++) {
            int row = g * 4 + r, col = w * 256 + f * 16 + ls;
            float e = __expf(acc[f][r] * sc - m[r]);
            sum[r] += e;
            P[(row * 1024 + col) ^ ((row & 7) << 3)] = f2bf(e);
        }
    #pragma unroll
    for (int d = 1; d < 16; d <<= 1)
        #pragma unroll
        for (int r = 0; r < 4; r++) sum[r] += __shfl_xor(sum[r], d, 64);
    if (ls == 0)
        #pragma unroll
        for (int r = 0; r < 4; r++) lbuf[w][g * 4 + r] = sum[r];
    __syncthreads();

    f32x4 o[8] = {};
    const bf16x8* Pv = reinterpret_cast<const bf16x8*>(P);
    const u16* Vp = vt + (size_t)b * 512 * 1024 + (size_t)(w * 128 + ls) * 1024 + g * 8;
    for (int k0 = 0; k0 < 1024; k0 += 32) {
        bf16x8 a = Pv[(ls * 128 + (k0 >> 3) + g) ^ (ls & 7)];
        #pragma unroll
        for (int q = 0; q < 8; q++) {
            bf16x8 bb = ldfrag(Vp + (size_t)q * 16 * 1024 + k0);
            o[q] = __builtin_amdgcn_mfma_f32_16x16x32_bf16(a, bb, o[q], 0, 0, 0);
        }
    }
    #pragma unroll
    for (int q = 0; q < 8; q++) {
        int col = w * 128 + q * 16 + ls;
        #pragma unroll
        for (int r = 0; r < 4; r++) {
            int row = g * 4 + r;
            float l = lbuf[0][row] + lbuf[1][row] + lbuf[2][row] + lbuf[3][row];
            attnO[(size_t)(b * 1024 + q0 + row) * 512 + col] = f2bf(o[q][r] / l);
        }
    }
}

// ---------------- proj Wo + residual(emb) + LayerNorm -> out1 (f32 + bf16)
__global__ __launch_bounds__(256) void k_projln(const u16* __restrict__ attnO, const u16* __restrict__ WoT,
                                                const float* __restrict__ emb, const float* __restrict__ gamma,
                                                const float* __restrict__ beta, float* __restrict__ out1f,
                                                u16* __restrict__ out1b) {
    __shared__ float buf[16][512];
    int m0 = blockIdx.x * 16;
    int lane = threadIdx.x & 63, w = threadIdx.x >> 6;
    int ls = lane & 15, g = lane >> 4;
    f32x4 acc[8] = {};
    const u16* Ap = attnO + (size_t)(m0 + ls) * 512 + g * 8;
    const u16* Bp = WoT + (size_t)(w * 128 + ls) * 512 + g * 8;
    for (int k0 = 0; k0 < 512; k0 += 32) {
        bf16x8 a = ldfrag(Ap + k0);
        #pragma unroll
        for (int q = 0; q < 8; q++) {
            bf16x8 bb = ldfrag(Bp + (size_t)q * 16 * 512 + k0);
            acc[q] = __builtin_amdgcn_mfma_f32_16x16x32_bf16(a, bb, acc[q], 0, 0, 0);
        }
    }
    #pragma unroll
    for (int q = 0; q < 8; q++) {
        int col = w * 128 + q * 16 + ls;
        #pragma unroll
        for (int r = 0; r < 4; r++) {
            int row = g * 4 + r;
            buf[row][col] = acc[q][r] + emb[(size_t)(m0 + row) * 512 + col];
        }
    }
    __syncthreads();
    int row = threadIdx.x >> 4, c0 = threadIdx.x & 15;
    float s = 0.f, s2 = 0.f;
    for (int c = c0; c < 512; c += 16) { float x = buf[row][c]; s += x; s2 += x * x; }
    #pragma unroll
    for (int d = 1; d < 16; d <<= 1) { s += __shfl_xor(s, d, 64); s2 += __shfl_xor(s2, d, 64); }
    float mu = s * (1.f / 512.f);
    float var = s2 * (1.f / 512.f) - mu * mu;
    float rs = rsqrtf(var + 1e-3f);
    for (int c = c0; c < 512; c += 16) {
        float y = gamma[c] * (buf[row][c] - mu) * rs + beta[c];
        out1f[(size_t)(m0 + row) * 512 + c] = y;
        out1b[(size_t)(m0 + row) * 512 + c] = f2bf(y);
    }
}

// ---------------- zero per-block step flags
__global__ __launch_bounds__(256) void k_init2(u32* flags) {
    int i = blockIdx.x * 256 + threadIdx.x;
    if (i < 16 * 1024) flags[i] = 0;
}

// ---------------- persistent LSTM scan: 16 blocks, all 1024 steps in-kernel.
// h exchange via relaxed agent-scope atomics (coherent at LLC). Per-step sync:
// vmcnt(0) drain of the 4B h-stores -> per-block flag store (distinct lines)
// -> wave0 lanes gather-poll all 16 flags in one vector load.
__global__ __launch_bounds__(256) void k_lstm(const u16* __restrict__ xpp, const u16* __restrict__ rT,
                                              void* hbufv, float* __restrict__ hseq, u32* flags) {
    int j = blockIdx.x;
    int tid = threadIdx.x;
    int lane = tid & 63, w = tid >> 6;
    int ls = lane & 15, g = lane >> 4;
    u32* hbG32 = (u32*)hbufv;
    ull* hbG64 = (ull*)hbufv;
    __shared__ float z[16][132];   // padded: 528B row stride spreads banks
    __shared__ u16 hb[8192];       // h[16][512], XOR-swizzled: byte ^= (row&7)<<4
    __shared__ u16 xb[2][2048];

    // R slice -> registers: wave w = gate w, cols j*32 + q*16+ls, k-octet kk*32+g*8
    bf16x8 rf[2][16];
    {
        const u16* Bp = rT + (size_t)(w * 512 + j * 32 + ls) * 512 + g * 8;
        #pragma unroll
        for (int q = 0; q < 2; q++)
            #pragma unroll
            for (int kk = 0; kk < 16; kk++)
                rf[q][kk] = ldfrag(Bp + (size_t)q * 16 * 512 + kk * 32);
    }
    float cA = 0.f, cB = 0.f;   // c-state for this thread's two (b,uu) pairs

    // h0 = 0 (built locally, no global round-trip)
    for (int i = tid; i < 4096; i += 256) ((u32*)hb)[i] = 0;
    // prologue: xpp[s=0] -> xb[0]
    {
        uint4 v = *reinterpret_cast<const uint4*>(xpp + ((size_t)j * 1024) * 2048 + tid * 8);
        *reinterpret_cast<uint4*>(&xb[0][tid * 8]) = v;
    }
    __syncthreads();

    int bb_ = tid >> 4, uu0 = (tid & 15) * 2;   // this thread's gate assignment

    for (int s = 0; s < 1024; s++) {
        // prefetch next step's xp chunk (independent of h)
        uint4 nx;
        if (s + 1 < 1024)
            nx = *reinterpret_cast<const uint4*>(xpp + ((size_t)j * 1024 + s + 1) * 2048 + tid * 8);

        // z = h @ R  (A-frags from swizzled LDS hb)
        f32x4 acc[2] = {};
        #pragma unroll
        for (int kk = 0; kk < 16; kk++) {
            int aidx = (ls * 512 + kk * 32 + g * 8) ^ ((ls & 7) << 3);
            bf16x8 a = ldfrag(&hb[aidx]);
            acc[0] = __builtin_amdgcn_mfma_f32_16x16x32_bf16(a, rf[0][kk], acc[0], 0, 0, 0);
            acc[1] = __builtin_amdgcn_mfma_f32_16x16x32_bf16(a, rf[1][kk], acc[1], 0, 0, 0);
        }
        #pragma unroll
        for (int q = 0; q < 2; q++)
            #pragma unroll
            for (int r = 0; r < 4; r++)
                z[g * 4 + r][w * 32 + q * 16 + ls] = acc[q][r];
        __syncthreads();

        // gates: thread t -> batch bb_, uu pair (uu0, uu0+1)
        float hres0, hres1;
        {
            const u16* xr = &xb[s & 1][bb_ * 128];
            #pragma unroll
            for (int p = 0; p < 2; p++) {
                int uu = uu0 + p;
                float zi = z[bb_][uu]      + bf2f(xr[uu]);
                float zf = z[bb_][32 + uu] + bf2f(xr[32 + uu]);
                float zg = z[bb_][64 + uu] + bf2f(xr[64 + uu]);
                float zo = z[bb_][96 + uu] + bf2f(xr[96 + uu]);
                float ii = 1.f / (1.f + __expf(-zi));
                float ff = 1.f / (1.f + __expf(-zf));
                float gg = fmaxf(zg, 0.f);
                float oo = 1.f / (1.f + __expf(-zo));
                float cp = p ? cB : cA;
                float cn = ff * cp + ii * gg;
                if (p) cB = cn; else cA = cn;
                float h = oo * fmaxf(cn, 0.f);
                if (p) hres1 = h; else hres0 = h;
            }
            u32 packed = (u32)f2bf(hres0) | ((u32)f2bf(hres1) << 16);
            __hip_atomic_store(hbG32 + ((s + 1) & 1) * 4096 + bb_ * 256 + ((j * 32 + uu0) >> 1),
                               packed, __ATOMIC_RELAXED, __HIP_MEMORY_SCOPE_AGENT);
        }
        if (s + 1 < 1024)
            *reinterpret_cast<uint4*>(&xb[(s + 1) & 1][tid * 8]) = nx;

        // release: drain the coherent h stores, then all-waves rendezvous
        asm volatile("s_waitcnt vmcnt(0)" ::: "memory");
        __syncthreads();   // all waves' h stores at LLC; LDS reads of z/hb done

        if (s + 1 < 1024) {
            if (tid == 0)
                __hip_atomic_store(flags + j * 1024 + s, 1u,
                                   __ATOMIC_RELAXED, __HIP_MEMORY_SCOPE_AGENT);
            // hseq store after the signal: HBM ack overlaps the poll
            *reinterpret_cast<float2*>(&hseq[((size_t)bb_ * 1024 + s) * 512 + j * 32 + uu0]) =
                make_float2(hres0, hres1);
            // wave0 lanes 0..15 gather-poll all 16 block flags in one load
            if (tid < 16 && tid != j) {
                const u32* f = flags + tid * 1024 + s;
                while (!__hip_atomic_load(f, __ATOMIC_RELAXED, __HIP_MEMORY_SCOPE_AGENT))
                    __builtin_amdgcn_s_sleep(2);
            }
            __syncthreads();
            asm volatile("" ::: "memory");
            // refill hb from coherent hbuf slot (s+1)&1 (2048 u64 per slot), swizzled
            const ull* src = hbG64 + ((s + 1) & 1) * 2048;
            #pragma unroll
            for (int i = 0; i < 8; i++) {
                int li = i * 256 + tid;           // coalesced: lanes -> consecutive u64
                int row = li >> 7;
                ((ull*)hb)[li ^ ((row & 7) << 1)] =
                    __hip_atomic_load(src + li, __ATOMIC_RELAXED, __HIP_MEMORY_SCOPE_AGENT);
            }
            __syncthreads();
        } else {
            *reinterpret_cast<float2*>(&hseq[((size_t)bb_ * 1024 + s) * 512 + j * 32 + uu0]) =
                make_float2(hres0, hres1);
        }
    }
}

// ---------------- final LN in place on d_out: out = LN(d_out + out1f)
__global__ __launch_bounds__(256) void k_finln(float* __restrict__ io, const float* __restrict__ res,
                                               const float* __restrict__ gamma, const float* __restrict__ beta) {
    int m0 = blockIdx.x * 16;
    int row = threadIdx.x >> 4, c0 = threadIdx.x & 15;
    size_t base = (size_t)(m0 + row) * 512;
    float x[32];
    float s = 0.f, s2 = 0.f;
    #pragma unroll
    for (int i = 0; i < 32; i++) {
        int cc = c0 + i * 16;
        x[i] = io[base + cc] + res[base + cc];
        s += x[i]; s2 += x[i] * x[i];
    }
    #pragma unroll
    for (int d = 1; d < 16; d <<= 1) { s += __shfl_xor(s, d, 64); s2 += __shfl_xor(s2, d, 64); }
    float mu = s * (1.f / 512.f);
    float var = s2 * (1.f / 512.f) - mu * mu;
    float rs = rsqrtf(var + 1e-3f);
    #pragma unroll
    for (int i = 0; i < 32; i++) {
        int cc = c0 + i * 16;
        io[base + cc] = gamma[cc] * (x[i] - mu) * rs + beta[cc];
    }
}

extern "C" void kernel_launch(void* const* d_in, const int* in_sizes, int n_in,
                              void* d_out, int out_size, void* d_ws, size_t ws_size,
                              hipStream_t stream) {
    (void)in_sizes; (void)n_in; (void)out_size; (void)ws_size;
    const float* emb   = (const float*)d_in[0];
    const float* Wq    = (const float*)d_in[1];
    const float* Wk    = (const float*)d_in[2];
    const float* Wv    = (const float*)d_in[3];
    const float* Wo    = (const float*)d_in[4];
    const float* gamma = (const float*)d_in[5];
    const float* beta  = (const float*)d_in[6];
    const float* lk    = (const float*)d_in[7];
    const float* lr    = (const float*)d_in[8];
    const float* lb    = (const float*)d_in[9];

    char* w = (char*)d_ws;
    size_t o = 0;
    u16* WqkvT = (u16*)(w + o); o += (size_t)1536 * 512 * 2;
    u16* WoT   = (u16*)(w + o); o += (size_t)512 * 512 * 2;
    u16* kT    = (u16*)(w + o); o += (size_t)2048 * 512 * 2;
    u16* rT    = (u16*)(w + o); o += (size_t)2048 * 512 * 2;
    u16* Xbf   = (u16*)(w + o); o += (size_t)16384 * 512 * 2;     // reused as attnO
    u16* QKV   = (u16*)(w + o); o += (size_t)16384 * 1536 * 2;    // reused (with Vt) as xpp
    u16* Vt    = (u16*)(w + o); o += (size_t)16 * 512 * 1024 * 2;
    float* out1f = (float*)(w + o); o += (size_t)16384 * 512 * 4;
    u16* out1b = (u16*)(w + o); o += (size_t)16384 * 512 * 2;
    void* hbuf = (void*)(w + o); o += (size_t)2 * 16 * 512 * 2;
    u32* flags = (u32*)(w + o);  o += (size_t)16 * 1024 * 4;
    u16* attnO = Xbf;   // Xbf dead after QKV GEMM
    u16* xpp   = QKV;   // QKV+Vt dead after attention
    float* outp = (float*)d_out;

    k_cvt<<<8192, 256, 0, stream>>>(emb, Xbf, 16384 * 512);
    k_tr_f2b<<<dim3(16, 16), 256, 0, stream>>>(Wq, WqkvT, 512, 512);
    k_tr_f2b<<<dim3(16, 16), 256, 0, stream>>>(Wk, WqkvT + 512 * 512, 512, 512);
    k_tr_f2b<<<dim3(16, 16), 256, 0, stream>>>(Wv, WqkvT + 1024 * 512, 512, 512);
    k_tr_f2b<<<dim3(16, 16), 256, 0, stream>>>(Wo, WoT, 512, 512);
    k_tr_f2b<<<dim3(64, 16), 256, 0, stream>>>(lk, kT, 512, 2048);
    k_tr_f2b<<<dim3(64, 16), 256, 0, stream>>>(lr, rT, 512, 2048);
    k_gemm<<<128 * 12, 256, 0, stream>>>(Xbf, WqkvT, QKV, nullptr, 16384, 1536, 512, 1536, 0);
    k_tr_v<<<dim3(32, 16, 16), 256, 0, stream>>>(QKV, Vt);
    k_attn<<<1024, 256, 0, stream>>>(QKV, Vt, attnO);
    k_projln<<<1024, 256, 0, stream>>>(attnO, WoT, emb, gamma, beta, out1f, out1b);
    k_gemm<<<128 * 16, 256, 0, stream>>>(out1b, kT, xpp, lb, 16384, 2048, 512, 2048, 1);
    k_init2<<<64, 256, 0, stream>>>(flags);
    k_lstm<<<16, 256, 0, stream>>>(xpp, rT, hbuf, outp, flags);
    k_finln<<<1024, 256, 0, stream>>>(outp, out1f, gamma, beta);
}